// Round 1
// baseline (1589.513 us; speedup 1.0000x reference)
//
#include <hip/hip_runtime.h>
#include <math.h>

// ---------------------------------------------------------------------------
// BnbQloraMLP: NF4 quant-dequant (block=64, absmax) of w1,w2,w3 then
//   out = (silu(x@w1^T) * (x@w2^T)) @ w3^T
// x: [4096,4096] f32, w1/w2: [11008,4096] f32, w3: [4096,11008] f32
// Strategy: dequant -> bf16 in ws, bf16 MFMA GEMMs (m97 128x128 template),
// dual-GEMM fuses gate/up + SwiGLU epilogue.
// ---------------------------------------------------------------------------

typedef __attribute__((ext_vector_type(4))) float f32x4;
typedef __attribute__((ext_vector_type(8))) short bf16x8;

#define DI __device__ __forceinline__

DI unsigned short f32_to_bf16(float f) {
  unsigned int u = __float_as_uint(f);
  u += 0x7FFFu + ((u >> 16) & 1u);   // round-to-nearest-even
  return (unsigned short)(u >> 16);
}

// NF4 codebook (exact f32 literals from bitsandbytes)
static constexpr float kCode[16] = {
    -1.0f, -0.6961928009986877f, -0.5250730514526367f, -0.39491748809814453f,
    -0.28444138169288635f, -0.18477343022823334f, -0.09105003625154495f, 0.0f,
    0.07958029955625534f, 0.16093020141124725f, 0.24611230194568634f,
    0.33791524171829224f, 0.44070982933044434f, 0.5626170039176941f,
    0.7229568362236023f, 1.0f};

// ---------------------------------------------------------------------------
// NF4 quant-dequant: 64-elem blocks. 16 lanes per block, 4 elems/lane (float4).
// Replicates jnp.searchsorted(bounds, v, 'left') == count(bounds[j] < v).
// ---------------------------------------------------------------------------
__global__ void __launch_bounds__(256) k_dequant_nf4(
    const float* __restrict__ in, unsigned short* __restrict__ out, int n4) {
  int i = blockIdx.x * 256 + threadIdx.x;
  if (i >= n4) return;
  f32x4 v = reinterpret_cast<const f32x4*>(in)[i];
  float am = fmaxf(fmaxf(fabsf(v.x), fabsf(v.y)), fmaxf(fabsf(v.z), fabsf(v.w)));
  // reduce absmax across the 16-lane group (one quant block)
  am = fmaxf(am, __shfl_xor(am, 1));
  am = fmaxf(am, __shfl_xor(am, 2));
  am = fmaxf(am, __shfl_xor(am, 4));
  am = fmaxf(am, __shfl_xor(am, 8));
  float scale = (am == 0.0f) ? 1.0f : am;
  unsigned short o[4];
#pragma unroll
  for (int j = 0; j < 4; ++j) {
    float nv = ((const float*)&v)[j] / scale;  // IEEE div, matches reference
    int idx = 0;
#pragma unroll
    for (int b = 0; b < 15; ++b)
      idx += (nv > 0.5f * (kCode[b] + kCode[b + 1])) ? 1 : 0;
    o[j] = f32_to_bf16(kCode[idx] * am);
  }
  ushort4 ov = make_ushort4(o[0], o[1], o[2], o[3]);
  reinterpret_cast<ushort4*>(out)[i] = ov;
}

__global__ void __launch_bounds__(256) k_f32_to_bf16(
    const float* __restrict__ in, unsigned short* __restrict__ out, int n4) {
  int i = blockIdx.x * 256 + threadIdx.x;
  if (i >= n4) return;
  f32x4 v = reinterpret_cast<const f32x4*>(in)[i];
  reinterpret_cast<ushort4*>(out)[i] =
      make_ushort4(f32_to_bf16(v.x), f32_to_bf16(v.y), f32_to_bf16(v.z), f32_to_bf16(v.w));
}

// ---------------------------------------------------------------------------
// GEMM helpers (m97 structure: 128x128 tile, BK=64, 4 waves, global_load_lds)
// ---------------------------------------------------------------------------
DI void gload16(const void* g, void* l) {
  __builtin_amdgcn_global_load_lds(
      (const __attribute__((address_space(1))) void*)g,
      (__attribute__((address_space(3))) void*)l, 16, 0, 0);
}

// Fused dual GEMM + SwiGLU:  H[m][n] = silu(X.W1^T) * (X.W2^T), bf16 out.
// X: [4096][4096] bf16, W1/W2: [11008][4096] bf16, H: [4096][11008] bf16
__global__ void __launch_bounds__(256, 2) k_gemm_dual_swiglu(
    const unsigned short* __restrict__ X,
    const unsigned short* __restrict__ W1,
    const unsigned short* __restrict__ W2,
    unsigned short* __restrict__ H) {
  constexpr int K = 4096, N = 11008;
  __shared__ unsigned short As[128 * 64];
  __shared__ unsigned short B1s[128 * 64];
  __shared__ unsigned short B2s[128 * 64];

  const int tid = threadIdx.x;
  const int w = tid >> 6, l = tid & 63;
  const int m0 = blockIdx.y * 128, n0 = blockIdx.x * 128;
  const int wr = w >> 1, wc = w & 1;

  // staging geometry: wave chunk = 8 rows x 64 cols (1024B), lane covers 16B
  const int srow = l >> 3;         // 0..7
  const int scol = (l & 7) * 8;    // 0..56

  f32x4 acc1[4][4] = {};
  f32x4 acc2[4][4] = {};

  for (int kt = 0; kt < K / 64; ++kt) {
    const int kb = kt * 64 + scol;
#pragma unroll
    for (int i = 0; i < 4; ++i) {
      const int c = w * 4 + i;
      const int r = c * 8 + srow;
      gload16(X + (size_t)(m0 + r) * K + kb, &As[c * 512]);
      gload16(W1 + (size_t)(n0 + r) * K + kb, &B1s[c * 512]);
      gload16(W2 + (size_t)(n0 + r) * K + kb, &B2s[c * 512]);
    }
    __syncthreads();
#pragma unroll
    for (int ks = 0; ks < 2; ++ks) {
      const int ko = ks * 32 + (l >> 4) * 8;
      bf16x8 a[4], b1[4], b2[4];
#pragma unroll
      for (int m = 0; m < 4; ++m)
        a[m] = *reinterpret_cast<const bf16x8*>(&As[(wr * 64 + m * 16 + (l & 15)) * 64 + ko]);
#pragma unroll
      for (int n = 0; n < 4; ++n) {
        b1[n] = *reinterpret_cast<const bf16x8*>(&B1s[(wc * 64 + n * 16 + (l & 15)) * 64 + ko]);
        b2[n] = *reinterpret_cast<const bf16x8*>(&B2s[(wc * 64 + n * 16 + (l & 15)) * 64 + ko]);
      }
#pragma unroll
      for (int m = 0; m < 4; ++m)
#pragma unroll
        for (int n = 0; n < 4; ++n) {
          acc1[m][n] = __builtin_amdgcn_mfma_f32_16x16x32_bf16(a[m], b1[n], acc1[m][n], 0, 0, 0);
          acc2[m][n] = __builtin_amdgcn_mfma_f32_16x16x32_bf16(a[m], b2[n], acc2[m][n], 0, 0, 0);
        }
    }
    __syncthreads();
  }

  // epilogue: silu(gate)*up -> bf16.  C/D layout: col = l&15, row = (l>>4)*4+j
  const int er = (l >> 4) * 4, ec = l & 15;
#pragma unroll
  for (int m = 0; m < 4; ++m)
#pragma unroll
    for (int n = 0; n < 4; ++n)
#pragma unroll
      for (int j = 0; j < 4; ++j) {
        float g = acc1[m][n][j];
        float u = acc2[m][n][j];
        float s = g / (1.0f + expf(-g));
        const int row = m0 + wr * 64 + m * 16 + er + j;
        const int col = n0 + wc * 64 + n * 16 + ec;
        H[(size_t)row * N + col] = f32_to_bf16(s * u);
      }
}

// Out[m][d] = H.W3^T :  H: [4096][11008] bf16, W3: [4096][11008] bf16, f32 out
__global__ void __launch_bounds__(256, 2) k_gemm_out(
    const unsigned short* __restrict__ Hm,
    const unsigned short* __restrict__ W3,
    float* __restrict__ Out) {
  constexpr int K = 11008, N = 4096;
  __shared__ unsigned short As[128 * 64];
  __shared__ unsigned short Bs[128 * 64];

  const int tid = threadIdx.x;
  const int w = tid >> 6, l = tid & 63;
  const int m0 = blockIdx.y * 128, n0 = blockIdx.x * 128;
  const int wr = w >> 1, wc = w & 1;

  const int srow = l >> 3;
  const int scol = (l & 7) * 8;

  f32x4 acc[4][4] = {};

  for (int kt = 0; kt < K / 64; ++kt) {
    const int kb = kt * 64 + scol;
#pragma unroll
    for (int i = 0; i < 4; ++i) {
      const int c = w * 4 + i;
      const int r = c * 8 + srow;
      gload16(Hm + (size_t)(m0 + r) * K + kb, &As[c * 512]);
      gload16(W3 + (size_t)(n0 + r) * K + kb, &Bs[c * 512]);
    }
    __syncthreads();
#pragma unroll
    for (int ks = 0; ks < 2; ++ks) {
      const int ko = ks * 32 + (l >> 4) * 8;
      bf16x8 a[4], b[4];
#pragma unroll
      for (int m = 0; m < 4; ++m)
        a[m] = *reinterpret_cast<const bf16x8*>(&As[(wr * 64 + m * 16 + (l & 15)) * 64 + ko]);
#pragma unroll
      for (int n = 0; n < 4; ++n)
        b[n] = *reinterpret_cast<const bf16x8*>(&Bs[(wc * 64 + n * 16 + (l & 15)) * 64 + ko]);
#pragma unroll
      for (int m = 0; m < 4; ++m)
#pragma unroll
        for (int n = 0; n < 4; ++n)
          acc[m][n] = __builtin_amdgcn_mfma_f32_16x16x32_bf16(a[m], b[n], acc[m][n], 0, 0, 0);
    }
    __syncthreads();
  }

  const int er = (l >> 4) * 4, ec = l & 15;
#pragma unroll
  for (int m = 0; m < 4; ++m)
#pragma unroll
    for (int n = 0; n < 4; ++n)
#pragma unroll
      for (int j = 0; j < 4; ++j) {
        const int row = m0 + wr * 64 + m * 16 + er + j;
        const int col = n0 + wc * 64 + n * 16 + ec;
        Out[(size_t)row * N + col] = acc[m][n][j];
      }
}

// ---------------------------------------------------------------------------
extern "C" void kernel_launch(void* const* d_in, const int* in_sizes, int n_in,
                              void* d_out, int out_size, void* d_ws, size_t ws_size,
                              hipStream_t stream) {
  const float* x  = (const float*)d_in[0];   // [4096,4096]
  const float* w1 = (const float*)d_in[1];   // [11008,4096]
  const float* w2 = (const float*)d_in[2];   // [11008,4096]
  const float* w3 = (const float*)d_in[3];   // [4096,11008]
  float* out = (float*)d_out;

  char* ws = (char*)d_ws;
  // layout (bytes): xb 32MiB | w1b 86MiB | w2b 86MiB | h 86MiB ; w3b reuses w1b
  unsigned short* xb  = (unsigned short*)(ws);
  unsigned short* w1b = (unsigned short*)(ws + 33554432);
  unsigned short* w2b = (unsigned short*)(ws + 123731968);
  unsigned short* hb  = (unsigned short*)(ws + 213909504);
  unsigned short* w3b = w1b;  // dequantized after gemm1 finishes (stream order)

  const int NW = 11008 * 4096 / 4;   // float4 groups per big weight
  k_f32_to_bf16<<<16384, 256, 0, stream>>>(x, xb, 4096 * 4096 / 4);
  k_dequant_nf4<<<NW / 256, 256, 0, stream>>>(w1, w1b, NW);
  k_dequant_nf4<<<NW / 256, 256, 0, stream>>>(w2, w2b, NW);

  // gate/up + SwiGLU -> h  (M=4096, N=11008, K=4096)
  k_gemm_dual_swiglu<<<dim3(86, 32), 256, 0, stream>>>(xb, w1b, w2b, hb);

  // w3 dequant into w1b's slot (safe: same-stream ordering)
  k_dequant_nf4<<<NW / 256, 256, 0, stream>>>(w3, w3b, NW);

  // out = h . w3^T  (M=4096, N=4096, K=11008)
  k_gemm_out<<<dim3(32, 32), 256, 0, stream>>>(hb, w3b, out);
}

// Round 2
// 1291.083 us; speedup vs baseline: 1.2311x; 1.2311x over previous
//
#include <hip/hip_runtime.h>
#include <math.h>

typedef __attribute__((ext_vector_type(4))) float f32x4;
typedef __attribute__((ext_vector_type(8))) short bf16x8;

#define DI __device__ __forceinline__

DI unsigned short f32_to_bf16(float f) {
  unsigned int u = __float_as_uint(f);
  u += 0x7FFFu + ((u >> 16) & 1u);   // round-to-nearest-even
  return (unsigned short)(u >> 16);
}

static constexpr float kCode[16] = {
    -1.0f, -0.6961928009986877f, -0.5250730514526367f, -0.39491748809814453f,
    -0.28444138169288635f, -0.18477343022823334f, -0.09105003625154495f, 0.0f,
    0.07958029955625534f, 0.16093020141124725f, 0.24611230194568634f,
    0.33791524171829224f, 0.44070982933044434f, 0.5626170039176941f,
    0.7229568362236023f, 1.0f};

// ---------------------------------------------------------------------------
// NF4 quant-dequant (block=64): 16 lanes/block, float4/lane.
// ---------------------------------------------------------------------------
__global__ void __launch_bounds__(256) k_dequant_nf4(
    const float* __restrict__ in, unsigned short* __restrict__ out, int n4) {
  int i = blockIdx.x * 256 + threadIdx.x;
  if (i >= n4) return;
  f32x4 v = reinterpret_cast<const f32x4*>(in)[i];
  float am = fmaxf(fmaxf(fabsf(v.x), fabsf(v.y)), fmaxf(fabsf(v.z), fabsf(v.w)));
  am = fmaxf(am, __shfl_xor(am, 1));
  am = fmaxf(am, __shfl_xor(am, 2));
  am = fmaxf(am, __shfl_xor(am, 4));
  am = fmaxf(am, __shfl_xor(am, 8));
  float scale = (am == 0.0f) ? 1.0f : am;
  unsigned short o[4];
#pragma unroll
  for (int j = 0; j < 4; ++j) {
    float nv = ((const float*)&v)[j] / scale;
    int idx = 0;
#pragma unroll
    for (int b = 0; b < 15; ++b)
      idx += (nv > 0.5f * (kCode[b] + kCode[b + 1])) ? 1 : 0;
    o[j] = f32_to_bf16(kCode[idx] * am);
  }
  reinterpret_cast<ushort4*>(out)[i] = make_ushort4(o[0], o[1], o[2], o[3]);
}

__global__ void __launch_bounds__(256) k_f32_to_bf16(
    const float* __restrict__ in, unsigned short* __restrict__ out, int n4) {
  int i = blockIdx.x * 256 + threadIdx.x;
  if (i >= n4) return;
  f32x4 v = reinterpret_cast<const f32x4*>(in)[i];
  reinterpret_cast<ushort4*>(out)[i] =
      make_ushort4(f32_to_bf16(v.x), f32_to_bf16(v.y), f32_to_bf16(v.z), f32_to_bf16(v.w));
}

// ---------------------------------------------------------------------------
// Pipelined GEMM common helpers
// ---------------------------------------------------------------------------
DI void gload16(const void* g, void* l) {
  __builtin_amdgcn_global_load_lds(
      (const __attribute__((address_space(1))) void*)g,
      (__attribute__((address_space(3))) void*)l, 16, 0, 0);
}

DI void barrier_nodrain() {
  asm volatile("" ::: "memory");
  __builtin_amdgcn_s_barrier();
  asm volatile("" ::: "memory");
}

#define WAITV(N) asm volatile("s_waitcnt vmcnt(" #N ")" ::: "memory")

// swizzle: involution on byte offsets within a 64B-row tile region.
// LDS is written linearly by global_load_lds from a pre-swizzled global
// source; ds_read applies the same XOR.  2-way bank aliasing only (free).

// ---------------------------------------------------------------------------
// Fused dual GEMM + SwiGLU. Tile 256(M)x128(N), BK=32, 8 waves (4Mx2N),
// 4 LDS buffers, prefetch distance 3, counted vmcnt(8).
// X:[4096][4096] bf16, W1/W2:[11008][4096] bf16 -> H:[4096][11008] bf16
// ---------------------------------------------------------------------------
__global__ void __launch_bounds__(512, 2) k_gemm_dual_swiglu(
    const unsigned short* __restrict__ X,
    const unsigned short* __restrict__ W1,
    const unsigned short* __restrict__ W2,
    unsigned short* __restrict__ H) {
  constexpr int K = 4096, N = 11008, NK = K / 32;
  __shared__ unsigned short lds[65536];  // 128 KiB
  char* ldsb = (char*)lds;
  // A: buf*16384 (0..64K) ; B1: 65536 + buf*8192 ; B2: 98304 + buf*8192

  const int tid = threadIdx.x;
  const int w = tid >> 6, l = tid & 63;

  // chunked XCD swizzle: 1376 blocks = 8 * 172
  const int bid = blockIdx.x;
  const int lt = (bid & 7) * 172 + (bid >> 3);
  const int mt = lt & 15, nt = lt >> 4;   // mtile fast: n-panel reuse per XCD
  const int m0 = mt * 256, n0 = nt * 128;

  const int wr = w >> 1, wc = w & 1;      // 4 x 2 waves

  // staging source precompute (per-lane logical row/col after inverse swizzle)
  const int o0 = w * 1024 + l * 16;                // byte off in 8KB chunk
  const int L0 = o0 ^ (((o0 >> 7) & 3) << 4);
  const int row0 = L0 >> 6;                        // 0..127
  const int col0 = (L0 & 63) >> 1;                 // 0,8,16,24
  const unsigned short* srcA = X  + (size_t)(m0 + row0) * K + col0;
  const unsigned short* srcB1 = W1 + (size_t)(n0 + row0) * K + col0;
  const unsigned short* srcB2 = W2 + (size_t)(n0 + row0) * K + col0;

#define DSTAGE_A(t)  { const int bf_ = (t) & 3;                                     \
    gload16(srcA + (size_t)(t) * 32,                 ldsb + bf_ * 16384 + (w << 10)); \
    gload16(srcA + (size_t)128 * K + (size_t)(t) * 32, ldsb + bf_ * 16384 + 8192 + (w << 10)); }
#define DSTAGE_B(t)  { const int bf_ = (t) & 3;                                     \
    gload16(srcB1 + (size_t)(t) * 32, ldsb + 65536 + bf_ * 8192 + (w << 10));        \
    gload16(srcB2 + (size_t)(t) * 32, ldsb + 98304 + bf_ * 8192 + (w << 10)); }

  // ds_read addresses (swizzled)
  const int slot = (l >> 4) * 16;
  const int rA = wr * 64 + (l & 15);
  const int offA0 = (rA * 64 + slot) ^ (((rA >> 1) & 3) << 4);  // +m*1024
  const int rB = wc * 64 + (l & 15);
  const int offB0 = (rB * 64 + slot) ^ (((rB >> 1) & 3) << 4);  // +n*1024

  f32x4 acc1[4][4] = {};
  f32x4 acc2[4][4] = {};

  // prologue: stage tiles 0,1,2 (12 insts); need tile0 -> allow 8 newest
  DSTAGE_A(0); DSTAGE_B(0); DSTAGE_A(1); DSTAGE_B(1); DSTAGE_A(2); DSTAGE_B(2);
  WAITV(8);
  barrier_nodrain();

  for (int kt = 0; kt < NK; ++kt) {
    const int buf = kt & 3;
    const char* abase  = ldsb + buf * 16384;
    const char* b1base = ldsb + 65536 + buf * 8192;
    const char* b2base = ldsb + 98304 + buf * 8192;
    bf16x8 a[4], b1[4], b2[4];
    // ---- phase A: stage A(kt+3); read A + B1; MFMA gate ----
    if (kt + 3 < NK) DSTAGE_A(kt + 3);
#pragma unroll
    for (int n = 0; n < 4; ++n) b1[n] = *(const bf16x8*)(b1base + (offB0 + n * 1024));
#pragma unroll
    for (int m = 0; m < 4; ++m) a[m] = *(const bf16x8*)(abase + (offA0 + m * 1024));
    __builtin_amdgcn_s_setprio(1);
#pragma unroll
    for (int m = 0; m < 4; ++m)
#pragma unroll
      for (int n = 0; n < 4; ++n)
        acc1[m][n] = __builtin_amdgcn_mfma_f32_16x16x32_bf16(a[m], b1[n], acc1[m][n], 0, 0, 0);
    __builtin_amdgcn_s_setprio(0);
    // ---- phase B: stage B(kt+3); read B2; MFMA up ----
    if (kt + 3 < NK) DSTAGE_B(kt + 3);
#pragma unroll
    for (int n = 0; n < 4; ++n) b2[n] = *(const bf16x8*)(b2base + (offB0 + n * 1024));
    __builtin_amdgcn_s_setprio(1);
#pragma unroll
    for (int m = 0; m < 4; ++m)
#pragma unroll
      for (int n = 0; n < 4; ++n)
        acc2[m][n] = __builtin_amdgcn_mfma_f32_16x16x32_bf16(a[m], b2[n], acc2[m][n], 0, 0, 0);
    __builtin_amdgcn_s_setprio(0);
    // ---- end-of-tile: ensure buf[(kt+1)&3] staged; never drain mid-loop ----
    if (kt + 1 < NK) {
      if (kt + 3 < NK)      WAITV(8);
      else if (kt + 2 < NK) WAITV(4);
      else                  WAITV(0);
      barrier_nodrain();
    }
  }

  // epilogue: silu(gate)*up -> bf16
  const int er = (l >> 4) * 4, ec = l & 15;
#pragma unroll
  for (int m = 0; m < 4; ++m)
#pragma unroll
    for (int n = 0; n < 4; ++n)
#pragma unroll
      for (int j = 0; j < 4; ++j) {
        float g = acc1[m][n][j];
        float u = acc2[m][n][j];
        float s = g / (1.0f + expf(-g));
        const int row = m0 + wr * 64 + m * 16 + er + j;
        const int col = n0 + wc * 64 + n * 16 + ec;
        H[(size_t)row * N + col] = f32_to_bf16(s * u);
      }
#undef DSTAGE_A
#undef DSTAGE_B
}

// ---------------------------------------------------------------------------
// Output GEMM. Tile 256x256, BK=32, 8 waves (2Mx4N), 4 buffers, vmcnt(8).
// H:[4096][11008] bf16, W3:[4096][11008] bf16 -> Out:[4096][4096] f32
// ---------------------------------------------------------------------------
__global__ void __launch_bounds__(512, 2) k_gemm_out(
    const unsigned short* __restrict__ Hm,
    const unsigned short* __restrict__ W3,
    float* __restrict__ Out) {
  constexpr int K = 11008, N = 4096, NK = K / 32;
  __shared__ unsigned short lds[65536];  // 128 KiB: A 4x16K | B 4x16K
  char* ldsb = (char*)lds;

  const int tid = threadIdx.x;
  const int w = tid >> 6, l = tid & 63;

  const int bid = blockIdx.x;             // 256 blocks = 8 * 32
  const int lt = (bid & 7) * 32 + (bid >> 3);
  const int mt = lt & 15, nt = lt >> 4;
  const int m0 = mt * 256, n0 = nt * 256;

  const int wr = w >> 2, wc = w & 3;      // 2 x 4 waves

  const int o0 = w * 1024 + l * 16;
  const int L0 = o0 ^ (((o0 >> 7) & 3) << 4);
  const int row0 = L0 >> 6;
  const int col0 = (L0 & 63) >> 1;
  const unsigned short* srcA = Hm + (size_t)(m0 + row0) * K + col0;
  const unsigned short* srcB = W3 + (size_t)(n0 + row0) * K + col0;

#define OSTAGE_A(t)  { const int bf_ = (t) & 3;                                       \
    gload16(srcA + (size_t)(t) * 32,                   ldsb + bf_ * 16384 + (w << 10)); \
    gload16(srcA + (size_t)128 * K + (size_t)(t) * 32, ldsb + bf_ * 16384 + 8192 + (w << 10)); }
#define OSTAGE_B(t)  { const int bf_ = (t) & 3;                                       \
    gload16(srcB + (size_t)(t) * 32,                   ldsb + 65536 + bf_ * 16384 + (w << 10)); \
    gload16(srcB + (size_t)128 * K + (size_t)(t) * 32, ldsb + 65536 + bf_ * 16384 + 8192 + (w << 10)); }

  const int slot = (l >> 4) * 16;
  const int rA = wr * 128 + (l & 15);
  const int offA0 = (rA * 64 + slot) ^ (((rA >> 1) & 3) << 4);  // +m*1024 (m=0..7)
  const int rB = wc * 64 + (l & 15);
  const int offB0 = (rB * 64 + slot) ^ (((rB >> 1) & 3) << 4);  // +n*1024

  f32x4 acc[8][4] = {};

  OSTAGE_A(0); OSTAGE_B(0); OSTAGE_A(1); OSTAGE_B(1); OSTAGE_A(2); OSTAGE_B(2);
  WAITV(8);
  barrier_nodrain();

  for (int kt = 0; kt < NK; ++kt) {
    const int buf = kt & 3;
    const char* abase = ldsb + buf * 16384;
    const char* bbase = ldsb + 65536 + buf * 16384;
    bf16x8 a[4], b[4];
    // ---- phase A: stage A(kt+3); read B + A(m0-3); MFMA m0-3 ----
    if (kt + 3 < NK) OSTAGE_A(kt + 3);
#pragma unroll
    for (int n = 0; n < 4; ++n) b[n] = *(const bf16x8*)(bbase + (offB0 + n * 1024));
#pragma unroll
    for (int m = 0; m < 4; ++m) a[m] = *(const bf16x8*)(abase + (offA0 + m * 1024));
    __builtin_amdgcn_s_setprio(1);
#pragma unroll
    for (int m = 0; m < 4; ++m)
#pragma unroll
      for (int n = 0; n < 4; ++n)
        acc[m][n] = __builtin_amdgcn_mfma_f32_16x16x32_bf16(a[m], b[n], acc[m][n], 0, 0, 0);
    __builtin_amdgcn_s_setprio(0);
    // ---- phase B: stage B(kt+3); read A(m4-7); MFMA m4-7 ----
    if (kt + 3 < NK) OSTAGE_B(kt + 3);
#pragma unroll
    for (int m = 0; m < 4; ++m) a[m] = *(const bf16x8*)(abase + (offA0 + 4096 + m * 1024));
    __builtin_amdgcn_s_setprio(1);
#pragma unroll
    for (int m = 0; m < 4; ++m)
#pragma unroll
      for (int n = 0; n < 4; ++n)
        acc[m + 4][n] = __builtin_amdgcn_mfma_f32_16x16x32_bf16(a[m], b[n], acc[m + 4][n], 0, 0, 0);
    __builtin_amdgcn_s_setprio(0);

    if (kt + 1 < NK) {
      if (kt + 3 < NK)      WAITV(8);
      else if (kt + 2 < NK) WAITV(4);
      else                  WAITV(0);
      barrier_nodrain();
    }
  }

  const int er = (l >> 4) * 4, ec = l & 15;
#pragma unroll
  for (int m = 0; m < 8; ++m)
#pragma unroll
    for (int n = 0; n < 4; ++n) {
      const int row = m0 + wr * 128 + m * 16 + er;
      const int col = n0 + wc * 64 + n * 16 + ec;
      float* p = Out + (size_t)row * N + col;
#pragma unroll
      for (int j = 0; j < 4; ++j) p[(size_t)j * N] = acc[m][n][j];
    }
#undef OSTAGE_A
#undef OSTAGE_B
}

// ---------------------------------------------------------------------------
extern "C" void kernel_launch(void* const* d_in, const int* in_sizes, int n_in,
                              void* d_out, int out_size, void* d_ws, size_t ws_size,
                              hipStream_t stream) {
  const float* x  = (const float*)d_in[0];   // [2,2048,4096] -> [4096][4096]
  const float* w1 = (const float*)d_in[1];   // [11008,4096]
  const float* w2 = (const float*)d_in[2];   // [11008,4096]
  const float* w3 = (const float*)d_in[3];   // [4096,11008]
  float* out = (float*)d_out;

  char* ws = (char*)d_ws;
  unsigned short* xb  = (unsigned short*)(ws);                // 32 MiB
  unsigned short* w1b = (unsigned short*)(ws + 33554432);     // 86 MiB
  unsigned short* w2b = (unsigned short*)(ws + 123731968);    // 86 MiB
  unsigned short* hb  = (unsigned short*)(ws + 213909504);    // 86 MiB
  unsigned short* w3b = w1b;  // reuse after gemm1 (stream-ordered)

  const int NW = 11008 * 4096 / 4;
  k_f32_to_bf16<<<16384, 256, 0, stream>>>(x, xb, 4096 * 4096 / 4);
  k_dequant_nf4<<<NW / 256, 256, 0, stream>>>(w1, w1b, NW);
  k_dequant_nf4<<<NW / 256, 256, 0, stream>>>(w2, w2b, NW);

  // gate/up + SwiGLU -> h  (M=4096, N=11008, K=4096) : 1376 = 16 x 86 tiles
  k_gemm_dual_swiglu<<<1376, 512, 0, stream>>>(xb, w1b, w2b, hb);

  k_dequant_nf4<<<NW / 256, 256, 0, stream>>>(w3, w3b, NW);

  // out = h . w3^T  (M=4096, N=4096, K=11008) : 256 = 16 x 16 tiles
  k_gemm_out<<<256, 512, 0, stream>>>(hb, w3b, out);
}